// Round 2
// baseline (970.855 us; speedup 1.0000x reference)
//
#include <hip/hip_runtime.h>
#include <hip/hip_bf16.h>

#define N_   64
#define C4_  64
#define V_   25
#define T_   128
#define K_   3
#define OC_  192   // C4_*K_

// ---------------- K1: acc + depthwise temporal conv (5-tap, same pad) -------
// acc = x_slice(branch) + z_prev (z_prev lives in out channels (branch-1)*64..)
// grid = N_*C4_*V_ blocks, 128 threads (t)
__global__ __launch_bounds__(128)
void k1_acc_conv(const float* __restrict__ x, const float* __restrict__ out,
                 const float* __restrict__ conv_w, const float* __restrict__ conv_b,
                 float* __restrict__ s, int branch) {
    __shared__ float row[T_ + 4];
    int bid = blockIdx.x;
    int v  = bid % V_;
    int nc = bid / V_;
    int c  = nc % C4_;
    int n  = nc / C4_;
    int t  = threadIdx.x;

    size_t xoff = ((size_t)(n * 256 + branch * C4_ + c) * V_ + v) * T_ + t;
    float a = x[xoff];
    if (branch > 0) {
        size_t zoff = ((size_t)(n * 256 + (branch - 1) * C4_ + c) * V_ + v) * T_ + t;
        a += out[zoff];
    }
    row[t + 2] = a;
    if (t < 2) { row[t] = 0.f; row[T_ + 2 + t] = 0.f; }
    __syncthreads();

    const float* wp = conv_w + (branch * C4_ + c) * 5;
    float r = conv_b[branch * C4_ + c]
            + wp[0] * row[t]     + wp[1] * row[t + 1] + wp[2] * row[t + 2]
            + wp[3] * row[t + 3] + wp[4] * row[t + 4];
    s[((size_t)(n * C4_ + c) * V_ + v) * T_ + t] = r;
}

// ---------------- K23: fused per-node 1x1 conv + adjacency + BN + LeakyReLU -
// y[n,o,w,t] = sum_cin W[w,o,cin] * s[n,cin,w,t]   (o = c*3+k, used only by c)
// z[n,c,v,t] = sum_{k,w} A[k,w,v] * y[n,c*3+k,w,t] -> BN -> LeakyReLU -> out
// grid = N_*32 blocks (c-pair per block), 128 threads (t)
__global__ __launch_bounds__(128)
void k23(const float* __restrict__ s, const float* __restrict__ gW,
         const float* __restrict__ A,
         const float* __restrict__ bng, const float* __restrict__ bnb,
         const float* __restrict__ bnm, const float* __restrict__ bnv,
         float* __restrict__ out, int branch) {
    int bid = blockIdx.x;
    int cg = bid % 32;           // c0 = cg*2
    int n  = bid / 32;
    int t  = threadIdx.x;

    float acc0[V_], acc1[V_];
    #pragma unroll
    for (int v = 0; v < V_; ++v) { acc0[v] = 0.f; acc1[v] = 0.f; }

    const float* sp = s + (size_t)n * C4_ * V_ * T_ + t;

    for (int w = 0; w < V_; ++w) {
        float yv[6] = {0.f, 0.f, 0.f, 0.f, 0.f, 0.f};   // [cLocal*3 + k]
        // W tile for this (branch, w): 6 consecutive o's starting at cg*6
        const float* Wb = gW + (((size_t)branch * V_ + w) * OC_ + cg * 6) * C4_;
        const float* srow = sp + (size_t)w * T_;
        #pragma unroll 8
        for (int cin = 0; cin < C4_; ++cin) {
            float sv = srow[(size_t)cin * (V_ * T_)];
            #pragma unroll
            for (int j = 0; j < 6; ++j)
                yv[j] += Wb[(size_t)j * C4_ + cin] * sv;   // uniform -> s_load
        }
        #pragma unroll
        for (int k = 0; k < K_; ++k) {
            const float* Ap = A + (k * V_ + w) * V_;
            float y0 = yv[k], y1 = yv[3 + k];
            #pragma unroll
            for (int v = 0; v < V_; ++v) {
                float av = Ap[v];                          // uniform -> s_load
                acc0[v] += av * y0;
                acc1[v] += av * y1;
            }
        }
    }

    #pragma unroll
    for (int cl = 0; cl < 2; ++cl) {
        int c = cg * 2 + cl;
        float g  = bng[branch * C4_ + c];
        float be = bnb[branch * C4_ + c];
        float mu = bnm[branch * C4_ + c];
        float va = bnv[branch * C4_ + c];
        float sc = g * rsqrtf(va + 1e-5f);
        float* op = out + ((size_t)(n * 256 + branch * C4_ + c) * V_) * T_ + t;
        const float* accp = cl ? acc1 : acc0;
        #pragma unroll
        for (int v = 0; v < V_; ++v) {
            float val = (accp[v] - mu) * sc + be;
            val = val > 0.f ? val : 0.2f * val;
            op[(size_t)v * T_] = val;
        }
    }
}

// ---------------- K4: passthrough split[3] -> out channels 192..255 ---------
// per-n contiguous chunk of 64*25*128 = 204800 floats = 51200 float4
__global__ __launch_bounds__(256)
void k4_copy(const float* __restrict__ x, float* __restrict__ out) {
    int i = blockIdx.x * blockDim.x + threadIdx.x;   // 0 .. 3,276,799
    int n = i / 51200;
    int j = i % 51200;
    const float4* src = (const float4*)(x + (size_t)(n * 256 + 192) * (V_ * T_));
    float4* dst = (float4*)(out + (size_t)(n * 256 + 192) * (V_ * T_));
    dst[j] = src[j];
}

extern "C" void kernel_launch(void* const* d_in, const int* in_sizes, int n_in,
                              void* d_out, int out_size, void* d_ws, size_t ws_size,
                              hipStream_t stream) {
    const float* x      = (const float*)d_in[0];
    const float* A      = (const float*)d_in[1];
    const float* conv_w = (const float*)d_in[2];
    const float* conv_b = (const float*)d_in[3];
    const float* gW     = (const float*)d_in[4];
    const float* bng    = (const float*)d_in[5];
    const float* bnb    = (const float*)d_in[6];
    const float* bnm    = (const float*)d_in[7];
    const float* bnv    = (const float*)d_in[8];
    float* out = (float*)d_out;

    float* s = (float*)d_ws;   // N*C4*V*T fp32 = 52,428,800 B

    for (int i = 0; i < 3; ++i) {
        hipLaunchKernelGGL(k1_acc_conv, dim3(N_ * C4_ * V_), dim3(T_), 0, stream,
                           x, out, conv_w, conv_b, s, i);
        hipLaunchKernelGGL(k23, dim3(N_ * 32), dim3(T_), 0, stream,
                           s, gW, A, bng, bnb, bnm, bnv, out, i);
    }
    hipLaunchKernelGGL(k4_copy, dim3(12800), dim3(256), 0, stream, x, out);
}